// Round 8
// baseline (416.449 us; speedup 1.0000x reference)
//
#include <hip/hip_runtime.h>

#define NPTS 65536
#define KC   1024
#define DD   512

using bf16x8 = __attribute__((ext_vector_type(8))) __bf16;
using f32x4  = __attribute__((ext_vector_type(4))) float;

// pack float4 -> 4 bf16 (truncation)
__device__ __forceinline__ uint2 pack4(const float4& v) {
  uint2 r;
  r.x = (__float_as_uint(v.x) >> 16) | (__float_as_uint(v.y) & 0xffff0000u);
  r.y = (__float_as_uint(v.z) >> 16) | (__float_as_uint(v.w) & 0xffff0000u);
  return r;
}

// ---------------- c2[k] = ||center_k||^2 (exact fp32) ----------------
__global__ __launch_bounds__(256) void c2_kernel(const float* __restrict__ centers,
                                                 float* __restrict__ c2) {
  int row = (blockIdx.x * 256 + threadIdx.x) >> 6;
  int lane = threadIdx.x & 63;
  const float4* c4 = (const float4*)(centers + (size_t)row * DD);
  float s = 0.f;
#pragma unroll
  for (int j = 0; j < 2; j++) {
    float4 v = c4[lane + 64 * j];
    s += v.x * v.x + v.y * v.y + v.z * v.z + v.w * v.w;
  }
#pragma unroll
  for (int off = 32; off; off >>= 1) s += __shfl_down(s, off, 64);
  if (lane == 0) c2[row] = s;
}

// ---------------- fused: convert + MFMA argmin + loss ----------------
// 256 threads = 4 waves (2m x 2n), wave tile 64x128.  BM=128, BN=256, BK=64.
// fp32 loaded from global, packed to bf16 in-register, staged to LDS with the
// conflict-free slot formula slot(r,oct) = r*8 + (oct ^ (r&7)).
// __launch_bounds__(256,2): 2 waves/EU -> 2 blocks/CU (R7's (512,2) gave ONE
// block/CU and serialized every barrier across the whole CU - never again).
// loss = sum(x2) + sum_m(c2[y[m]] - 2*dot(x_m,c_y[m])), captured in the fold.
__global__ __launch_bounds__(256, 2) void fused_kernel(
    const float* __restrict__ x, const float* __restrict__ centers,
    const float* __restrict__ c2g, const int* __restrict__ y,
    float* __restrict__ ynew_out, float* __restrict__ ploss) {
  __shared__ uint4 As[1024];    // 128 rows x 8 octs (16 KB)
  __shared__ uint4 Bs[2048];    // 256 rows x 8 octs (32 KB)
  __shared__ float c2s[1024];
  __shared__ int   ys[128];
  __shared__ float vS[2][128];
  __shared__ int   iS[2][128];
  __shared__ float lred[4];

  const int t = threadIdx.x;           // 0..255
  const int w = t >> 6, l = t & 63;
  const int wm = w >> 1, wn = w & 1;   // wave tile: rows wm*64+, cols wn*128+
  const int q4 = l >> 4, m16 = l & 15;
  const int row0 = blockIdx.x * 128;

#pragma unroll
  for (int i = 0; i < 4; i++) c2s[t + 256 * i] = c2g[t + 256 * i];
  if (t < 128) ys[t] = y[row0 + t];
  __syncthreads();

  int ysv[16];
#pragma unroll
  for (int i = 0; i < 4; i++)
#pragma unroll
    for (int r = 0; r < 4; r++)
      ysv[i * 4 + r] = ys[wm * 64 + i * 16 + q4 * 4 + r];

  // A staging: thread -> row t>>1 (0..127), 4-oct half ah = t&1.
  const int ar = t >> 1, ah = t & 1;
  const float4* ag = (const float4*)x + (size_t)(row0 + ar) * 128 + ah * 8;
  int aslot[4];
#pragma unroll
  for (int j = 0; j < 4; j++) aslot[j] = ar * 8 + ((ah * 4 + j) ^ (ar & 7));

  // B staging: thread -> row t (0..255), all 8 octs of the 64-k window.
  const int br = t;
  int bslot[8];
#pragma unroll
  for (int j = 0; j < 8; j++) bslot[j] = br * 8 + (j ^ (br & 7));

  float best[16];
  int bi_[16];
#pragma unroll
  for (int i = 0; i < 16; i++) { best[i] = 3.4e38f; bi_[i] = 0; }
  float lsum = 0.f, x2s = 0.f;

  for (int n0 = 0; n0 < KC; n0 += 256) {
    f32x4 acc[4][8];
#pragma unroll
    for (int i = 0; i < 4; i++)
#pragma unroll
      for (int j = 0; j < 8; j++) acc[i][j] = (f32x4){0.f, 0.f, 0.f, 0.f};

    const float4* bg = (const float4*)centers + (size_t)(n0 + br) * 128;

    for (int ks = 0; ks < 8; ks++) {
      // fp32 global loads + in-register bf16 pack
      float4 av[8];
#pragma unroll
      for (int j = 0; j < 8; j++) av[j] = ag[ks * 16 + j];
      float4 bv[16];
#pragma unroll
      for (int j = 0; j < 16; j++) bv[j] = bg[ks * 16 + j];
      if (n0 == 0) {  // exact fp32 x2, each element exactly once (pass 0)
#pragma unroll
        for (int j = 0; j < 8; j++)
          x2s += av[j].x * av[j].x + av[j].y * av[j].y +
                 av[j].z * av[j].z + av[j].w * av[j].w;
      }
      uint2 pa[8], pb[16];
#pragma unroll
      for (int j = 0; j < 8; j++) pa[j] = pack4(av[j]);
#pragma unroll
      for (int j = 0; j < 16; j++) pb[j] = pack4(bv[j]);
      __syncthreads();  // previous window's fragment reads complete
#pragma unroll
      for (int j = 0; j < 4; j++)
        As[aslot[j]] = make_uint4(pa[2 * j].x, pa[2 * j].y,
                                  pa[2 * j + 1].x, pa[2 * j + 1].y);
#pragma unroll
      for (int j = 0; j < 8; j++)
        Bs[bslot[j]] = make_uint4(pb[2 * j].x, pb[2 * j].y,
                                  pb[2 * j + 1].x, pb[2 * j + 1].y);
      __syncthreads();  // staging complete
#pragma unroll
      for (int kk = 0; kk < 2; kk++) {
        const int oct = kk * 4 + q4;
        bf16x8 af[4];
#pragma unroll
        for (int i = 0; i < 4; i++) {
          const int ra = wm * 64 + i * 16 + m16;
          af[i] = *(const bf16x8*)&As[ra * 8 + (oct ^ (m16 & 7))];
        }
#pragma unroll
        for (int j = 0; j < 8; j++) {
          const int rb = wn * 128 + j * 16 + m16;
          bf16x8 bf = *(const bf16x8*)&Bs[rb * 8 + (oct ^ (m16 & 7))];
#pragma unroll
          for (int i = 0; i < 4; i++)
            acc[i][j] = __builtin_amdgcn_mfma_f32_16x16x32_bf16(af[i], bf, acc[i][j], 0, 0, 0);
        }
      }
    }

    // fold: argmin + loss capture.  C/D: col=lane&15, row=(lane>>4)*4+reg
#pragma unroll
    for (int j = 0; j < 8; j++) {
      const int n = n0 + wn * 128 + j * 16 + m16;
      const float cc = c2s[n];
#pragma unroll
      for (int i = 0; i < 4; i++)
#pragma unroll
        for (int r = 0; r < 4; r++) {
          float v = fmaf(-2.f, acc[i][j][r], cc);
          const int bi = i * 4 + r;
          if (n == ysv[bi]) lsum += v;
          if (v < best[bi]) { best[bi] = v; bi_[bi] = n; }
        }
    }
  }

  // per-wave reduce across the 16 m16 lanes, then cross-wave (wn) via LDS
#pragma unroll
  for (int bi = 0; bi < 16; bi++) {
    float v = best[bi];
    int idx = bi_[bi];
#pragma unroll
    for (int off = 8; off; off >>= 1) {
      float ov = __shfl_xor(v, off, 64);
      int oi = __shfl_xor(idx, off, 64);
      if (ov < v || (ov == v && oi < idx)) { v = ov; idx = oi; }
    }
    if (m16 == 0) {
      const int r128 = wm * 64 + (bi >> 2) * 16 + q4 * 4 + (bi & 3);
      vS[wn][r128] = v;
      iS[wn][r128] = idx;
    }
  }
  __syncthreads();
  if (t < 128) {
    float v = vS[0][t];
    int idx = iS[0][t];
    float ov = vS[1][t];
    int oi = iS[1][t];
    if (ov < v || (ov == v && oi < idx)) { v = ov; idx = oi; }
    ynew_out[row0 + t] = (float)idx;
  }

  // loss partial: bf16 dot terms + exact x2
  lsum += x2s;
#pragma unroll
  for (int off = 32; off; off >>= 1) lsum += __shfl_down(lsum, off, 64);
  if (l == 0) lred[w] = lsum;
  __syncthreads();
  if (t == 0) ploss[blockIdx.x] = lred[0] + lred[1] + lred[2] + lred[3];
}

// out[0] = sum(ploss[512])
__global__ __launch_bounds__(256) void loss_final(const float* __restrict__ ploss,
                                                  float* __restrict__ out) {
  float s = ploss[threadIdx.x] + ploss[threadIdx.x + 256];
#pragma unroll
  for (int off = 32; off; off >>= 1) s += __shfl_down(s, off, 64);
  __shared__ float ps[4];
  if ((threadIdx.x & 63) == 0) ps[threadIdx.x >> 6] = s;
  __syncthreads();
  if (threadIdx.x == 0) out[0] = ps[0] + ps[1] + ps[2] + ps[3];
}

// ================= launcher =================

extern "C" void kernel_launch(void* const* d_in, const int* in_sizes, int n_in,
                              void* d_out, int out_size, void* d_ws, size_t ws_size,
                              hipStream_t stream) {
  const float* x       = (const float*)d_in[0];
  const int*   y       = (const int*)d_in[1];
  const float* centers = (const float*)d_in[2];
  float* out = (float*)d_out;  // out[0] = loss, out[1..] = ynew as float

  float* c2    = (float*)d_ws;  // KC floats
  float* ploss = c2 + KC;       // 512 floats

  c2_kernel<<<KC / 4, 256, 0, stream>>>(centers, c2);
  fused_kernel<<<NPTS / 128, 256, 0, stream>>>(x, centers, c2, y, out + 1, ploss);
  loss_final<<<1, 256, 0, stream>>>(ploss, out);
}

// Round 9
// 270.876 us; speedup vs baseline: 1.5374x; 1.5374x over previous
//
#include <hip/hip_runtime.h>

#define NPTS 65536
#define KC   1024
#define DD   512

using bf16x8 = __attribute__((ext_vector_type(8))) __bf16;
using f32x4  = __attribute__((ext_vector_type(4))) float;

// ---- async global->LDS, 16B per lane. LDS dest = wave-uniform base + lane*16.
// Zero VGPR cost for staging — this is why the pre-converted-workspace GEMM is
// the only register-feasible shape (R5/R8: in-register staging spilled the
// 128-AGPR accumulator; WRITE_SIZE 83-85 MB both times).
__device__ __forceinline__ void gld_lds16(const void* g, void* lds_base) {
  __builtin_amdgcn_global_load_lds(
      (const __attribute__((address_space(1))) unsigned int*)(uintptr_t)g,
      (__attribute__((address_space(3))) unsigned int*)(unsigned int)(uintptr_t)lds_base,
      16, 0, 0);
}

// pack float4 -> 4 bf16 (truncation)
__device__ __forceinline__ uint2 pack4(const float4& v) {
  uint2 r;
  r.x = (__float_as_uint(v.x) >> 16) | (__float_as_uint(v.y) & 0xffff0000u);
  r.y = (__float_as_uint(v.z) >> 16) | (__float_as_uint(v.w) & 0xffff0000u);
  return r;
}

// ================= FAST PATH =================

// merged prep: blocks [0,16384) = one wave per x row: convert x->bf16 and
// accumulate the exact-fp32 loss term ||x_i - c_{y[i]}||^2 (gathered center
// row is L2/L3-hot).  blocks [16384,16640) = centers->cb + c2.
__global__ __launch_bounds__(256) void prep_kernel(
    const float* __restrict__ x, const int* __restrict__ y,
    const float* __restrict__ centers, uint4* __restrict__ xb,
    uint4* __restrict__ cb, float* __restrict__ c2,
    float* __restrict__ partial) {
  const int w = threadIdx.x >> 6, l = threadIdx.x & 63;
  if (blockIdx.x >= 16384) {   // centers section
    const int row = (blockIdx.x - 16384) * 4 + w;
    const float4* cf4 = (const float4*)centers;
    float4 a = cf4[row * 128 + 2 * l];
    float4 b = cf4[row * 128 + 2 * l + 1];
    uint2 pa = pack4(a), pb = pack4(b);
    cb[row * 64 + l] = make_uint4(pa.x, pa.y, pb.x, pb.y);
    float s = a.x * a.x + a.y * a.y + a.z * a.z + a.w * a.w +
              b.x * b.x + b.y * b.y + b.z * b.z + b.w * b.w;
#pragma unroll
    for (int off = 32; off; off >>= 1) s += __shfl_down(s, off, 64);
    if (l == 0) c2[row] = s;
    return;
  }
  const int row = blockIdx.x * 4 + w;
  const float4* xr = (const float4*)(x + (size_t)row * DD);
  float4 a = xr[2 * l];
  float4 b = xr[2 * l + 1];
  uint2 pa = pack4(a), pb = pack4(b);
  xb[row * 64 + l] = make_uint4(pa.x, pa.y, pb.x, pb.y);
  const int yr = y[row];
  const float4* cr = (const float4*)(centers + (size_t)yr * DD);
  float4 ca = cr[2 * l];
  float4 cb2 = cr[2 * l + 1];
  float d0 = a.x - ca.x, d1 = a.y - ca.y, d2 = a.z - ca.z, d3 = a.w - ca.w;
  float d4 = b.x - cb2.x, d5 = b.y - cb2.y, d6 = b.z - cb2.z, d7 = b.w - cb2.w;
  float s = d0 * d0 + d1 * d1 + d2 * d2 + d3 * d3 +
            d4 * d4 + d5 * d5 + d6 * d6 + d7 * d7;
#pragma unroll
  for (int off = 32; off; off >>= 1) s += __shfl_down(s, off, 64);
  __shared__ float ps[4];
  if (l == 0) ps[w] = s;
  __syncthreads();
  if (threadIdx.x == 0) partial[blockIdx.x] = ps[0] + ps[1] + ps[2] + ps[3];
}

// bf16 MFMA argmin, BM=128 x BN=256, BK=64.  64 MFMA per barrier window.
// __launch_bounds__(256,2): unified VGPR+AGPR pool is 512/SIMD; this kernel
// needs ~236 regs/wave (128 AGPR acc + ~108 VGPR) -> 2 waves/SIMD max.
// (256,3) forced a 170-reg cap -> 85 MB accumulator spill (R5). Never again.
__global__ __launch_bounds__(256, 2) void gemm_argmin(
    const uint4* __restrict__ xb, const uint4* __restrict__ cb,
    const float* __restrict__ c2, float* __restrict__ ynew_out) {
  __shared__ uint4 As[1024];   // 128 rows x 8 slots (64 bf16/row chunk)
  __shared__ uint4 Bs[2048];   // 256 rows x 8 slots
  __shared__ float c2s[1024];

  const int t = threadIdx.x;
  const int w = t >> 6, l = t & 63;
  const int wm = w >> 1, wn = w & 1;   // wave: 64 rows x 128 cols
  const int q4 = l >> 4, m16 = l & 15;
  const int row0 = blockIdx.x * 128;

#pragma unroll
  for (int i = 0; i < 4; i++) c2s[t + 256 * i] = c2[t + 256 * i];

  // staging lane mapping: chunk covers 8 rows; lane l -> row l>>3, slot l&7,
  // source oct (l&7)^(l>>3)  => LDS slot(r,oct) = oct ^ (r&7)  (conflict-free)
  const int r_l = l >> 3;
  const int o_l = (l & 7) ^ r_l;
  int aidx[4];
#pragma unroll
  for (int q = 0; q < 4; q++)
    aidx[q] = (row0 + (w * 4 + q) * 8 + r_l) * 64 + o_l;
  int bsrc[8];
#pragma unroll
  for (int q = 0; q < 8; q++)
    bsrc[q] = ((w * 8 + q) * 8 + r_l) * 64 + o_l;

  const int xr = m16 & 7;

  float best[16];
  int bi_[16];
#pragma unroll
  for (int i = 0; i < 16; i++) { best[i] = 3.4e38f; bi_[i] = 0; }

  for (int n0 = 0; n0 < KC; n0 += 256) {
    f32x4 acc[4][8];
#pragma unroll
    for (int i = 0; i < 4; i++)
#pragma unroll
      for (int j = 0; j < 8; j++) acc[i][j] = (f32x4){0.f, 0.f, 0.f, 0.f};

    const uint4* bbase = cb + n0 * 64;

    for (int ks = 0; ks < 8; ks++) {
      __syncthreads();  // previous iteration's fragment reads complete
#pragma unroll
      for (int q = 0; q < 4; q++)
        gld_lds16(xb + aidx[q] + ks * 8, &As[(w * 4 + q) * 64]);
#pragma unroll
      for (int q = 0; q < 8; q++)
        gld_lds16(bbase + bsrc[q] + ks * 8, &Bs[(w * 8 + q) * 64]);
      __syncthreads();  // staging complete
#pragma unroll
      for (int kk = 0; kk < 2; kk++) {
        const int oct = kk * 4 + q4;
        bf16x8 af[4];
#pragma unroll
        for (int i = 0; i < 4; i++) {
          const int ra = wm * 64 + i * 16 + m16;
          af[i] = *(const bf16x8*)&As[ra * 8 + (oct ^ xr)];
        }
#pragma unroll
        for (int j = 0; j < 8; j++) {
          const int rb = wn * 128 + j * 16 + m16;
          bf16x8 bf = *(const bf16x8*)&Bs[rb * 8 + (oct ^ xr)];
#pragma unroll
          for (int i = 0; i < 4; i++)
            acc[i][j] = __builtin_amdgcn_mfma_f32_16x16x32_bf16(af[i], bf, acc[i][j], 0, 0, 0);
        }
      }
    }

    // fold tile into running argmin.  C/D: col=lane&15, row=(lane>>4)*4+reg
#pragma unroll
    for (int j = 0; j < 8; j++) {
      const int n = n0 + wn * 128 + j * 16 + m16;
      const float cc = c2s[n];
#pragma unroll
      for (int i = 0; i < 4; i++)
#pragma unroll
        for (int r = 0; r < 4; r++) {
          float v = fmaf(-2.f, acc[i][j][r], cc);
          const int bi = i * 4 + r;
          if (v < best[bi]) { best[bi] = v; bi_[bi] = n; }
        }
    }
  }

#pragma unroll
  for (int bi = 0; bi < 16; bi++) {
    float v = best[bi];
    int idx = bi_[bi];
#pragma unroll
    for (int off = 8; off; off >>= 1) {
      float ov = __shfl_xor(v, off, 64);
      int oi = __shfl_xor(idx, off, 64);
      if (ov < v || (ov == v && oi < idx)) { v = ov; idx = oi; }
    }
    if (m16 == 0) {
      const int m = wm * 64 + (bi >> 2) * 16 + q4 * 4 + (bi & 3);
      ynew_out[row0 + m] = (float)idx;
    }
  }
}

__global__ __launch_bounds__(256) void loss_final(const float* __restrict__ partial,
                                                  float* __restrict__ out) {
  float s = 0.f;
#pragma unroll
  for (int j = 0; j < 64; j++) s += partial[threadIdx.x + 256 * j];
#pragma unroll
  for (int off = 32; off; off >>= 1) s += __shfl_down(s, off, 64);
  __shared__ float ps[4];
  if ((threadIdx.x & 63) == 0) ps[threadIdx.x >> 6] = s;
  __syncthreads();
  if (threadIdx.x == 0) out[0] = ps[0] + ps[1] + ps[2] + ps[3];
}

// ================= FALLBACK PATH (R2, used only if ws too small) =================

#define SLOT(row, oct) (16 * (oct) + (((row) & 15) ^ (((oct) & 2) << 1)))

__device__ __forceinline__ void split_pack(const float4& a, const float4& b,
                                           uint4& hi, uint4& lo) {
  float f[8] = {a.x, a.y, a.z, a.w, b.x, b.y, b.z, b.w};
  uint hw[4], lw[4];
#pragma unroll
  for (int i = 0; i < 4; i++) {
    uint e0 = __float_as_uint(f[2 * i]), e1 = __float_as_uint(f[2 * i + 1]);
    hw[i] = (e0 >> 16) | (e1 & 0xffff0000u);
    float l0 = f[2 * i]     - __uint_as_float(e0 & 0xffff0000u);
    float l1 = f[2 * i + 1] - __uint_as_float(e1 & 0xffff0000u);
    lw[i] = (__float_as_uint(l0) >> 16) | (__float_as_uint(l1) & 0xffff0000u);
  }
  hi = make_uint4(hw[0], hw[1], hw[2], hw[3]);
  lo = make_uint4(lw[0], lw[1], lw[2], lw[3]);
}

__global__ __launch_bounds__(256) void c2_kernel(const float* __restrict__ centers,
                                                 float* __restrict__ c2) {
  int wave = (blockIdx.x * 256 + threadIdx.x) >> 6;
  int lane = threadIdx.x & 63;
  const float4* c4 = (const float4*)(centers + (size_t)wave * DD);
  float s = 0.f;
#pragma unroll
  for (int j = 0; j < 2; j++) {
    float4 v = c4[lane + 64 * j];
    s += v.x * v.x + v.y * v.y + v.z * v.z + v.w * v.w;
  }
#pragma unroll
  for (int off = 32; off; off >>= 1) s += __shfl_down(s, off, 64);
  if (lane == 0) c2[wave] = s;
}

__global__ __launch_bounds__(256, 2) void argmin_fb(
    const float* __restrict__ x, const float* __restrict__ centers,
    const float* __restrict__ c2, float* __restrict__ ynew_out) {
  __shared__ uint4 Ah[512], Al[512], Bh[512], Bl[512];
  const int t = threadIdx.x;
  const int w = t >> 6, l = t & 63;
  const int wm = w >> 1, wn = w & 1;
  const size_t row0 = (size_t)blockIdx.x * 128;
  const int srow = t >> 1, h = t & 1;
  const int mt = srow >> 4;
  const int so0 = mt * 64 + SLOT(srow, 2 * h);
  const int so1 = mt * 64 + SLOT(srow, 2 * h + 1);
  const int rs = SLOT(l & 15, l >> 4);
  const float* xp = x + (row0 + srow) * DD + h * 16;
  float best[16];
  int bidx[16];
#pragma unroll
  for (int i = 0; i < 16; i++) { best[i] = 3.4e38f; bidx[i] = 0; }
  for (int n0 = 0; n0 < KC; n0 += 128) {
    const float* bp = centers + (size_t)(n0 + srow) * DD + h * 16;
    f32x4 acc[4][4];
#pragma unroll
    for (int i = 0; i < 4; i++)
#pragma unroll
      for (int j = 0; j < 4; j++) acc[i][j] = (f32x4){0.f, 0.f, 0.f, 0.f};
    float4 ra[4], rb[4];
#pragma unroll
    for (int q = 0; q < 4; q++) {
      ra[q] = *(const float4*)(xp + q * 4);
      rb[q] = *(const float4*)(bp + q * 4);
    }
    for (int ks = 0; ks < 16; ks++) {
      uint4 ah0, al0, ah1, al1, bh0, bl0, bh1, bl1;
      split_pack(ra[0], ra[1], ah0, al0);
      split_pack(ra[2], ra[3], ah1, al1);
      split_pack(rb[0], rb[1], bh0, bl0);
      split_pack(rb[2], rb[3], bh1, bl1);
      __syncthreads();
      Ah[so0] = ah0; Al[so0] = al0;
      Ah[so1] = ah1; Al[so1] = al1;
      Bh[so0] = bh0; Bl[so0] = bl0;
      Bh[so1] = bh1; Bl[so1] = bl1;
      __syncthreads();
      if (ks < 15) {
#pragma unroll
        for (int q = 0; q < 4; q++) {
          ra[q] = *(const float4*)(xp + (ks + 1) * 32 + q * 4);
          rb[q] = *(const float4*)(bp + (ks + 1) * 32 + q * 4);
        }
      }
      bf16x8 afh[4], afl[4], bfh[4], bfl[4];
#pragma unroll
      for (int i = 0; i < 4; i++) {
        afh[i] = *(const bf16x8*)&Ah[(wm * 4 + i) * 64 + rs];
        afl[i] = *(const bf16x8*)&Al[(wm * 4 + i) * 64 + rs];
        bfh[i] = *(const bf16x8*)&Bh[(wn * 4 + i) * 64 + rs];
        bfl[i] = *(const bf16x8*)&Bl[(wn * 4 + i) * 64 + rs];
      }
#pragma unroll
      for (int i = 0; i < 4; i++)
#pragma unroll
        for (int j = 0; j < 4; j++) {
          acc[i][j] = __builtin_amdgcn_mfma_f32_16x16x32_bf16(afh[i], bfh[j], acc[i][j], 0, 0, 0);
          acc[i][j] = __builtin_amdgcn_mfma_f32_16x16x32_bf16(afl[i], bfh[j], acc[i][j], 0, 0, 0);
          acc[i][j] = __builtin_amdgcn_mfma_f32_16x16x32_bf16(afh[i], bfl[j], acc[i][j], 0, 0, 0);
        }
    }
#pragma unroll
    for (int j = 0; j < 4; j++) {
      int n = n0 + wn * 64 + j * 16 + (l & 15);
      float cc = c2[n];
#pragma unroll
      for (int i = 0; i < 4; i++)
#pragma unroll
        for (int r = 0; r < 4; r++) {
          float v = fmaf(-2.f, acc[i][j][r], cc);
          int bi = i * 4 + r;
          if (v < best[bi]) { best[bi] = v; bidx[bi] = n; }
        }
    }
  }
#pragma unroll
  for (int bi = 0; bi < 16; bi++) {
    float v = best[bi];
    int idx = bidx[bi];
#pragma unroll
    for (int off = 8; off; off >>= 1) {
      float ov = __shfl_xor(v, off, 64);
      int oi = __shfl_xor(idx, off, 64);
      if (ov < v || (ov == v && oi < idx)) { v = ov; idx = oi; }
    }
    if ((l & 15) == 0) {
      int m = wm * 64 + (bi >> 2) * 16 + (l >> 4) * 4 + (bi & 3);
      ynew_out[row0 + m] = (float)idx;
    }
  }
}

__global__ __launch_bounds__(256) void loss_partial_fb(
    const float* __restrict__ x, const int* __restrict__ y,
    const float* __restrict__ centers, float* __restrict__ partial) {
  const int w = threadIdx.x >> 6, l = threadIdx.x & 63;
  const int row = blockIdx.x * 4 + w;
  const float4* x4 = (const float4*)(x + (size_t)row * DD);
  const float4* c4 = (const float4*)(centers + (size_t)y[row] * DD);
  float s = 0.f;
#pragma unroll
  for (int j = 0; j < 2; j++) {
    float4 xv = x4[2 * l + j], cv = c4[2 * l + j];
    float dx = xv.x - cv.x, dy = xv.y - cv.y, dz = xv.z - cv.z, dw = xv.w - cv.w;
    s += dx * dx + dy * dy + dz * dz + dw * dw;
  }
#pragma unroll
  for (int off = 32; off; off >>= 1) s += __shfl_down(s, off, 64);
  __shared__ float ps[4];
  if (l == 0) ps[w] = s;
  __syncthreads();
  if (threadIdx.x == 0) partial[blockIdx.x] = ps[0] + ps[1] + ps[2] + ps[3];
}

// ================= launcher =================

extern "C" void kernel_launch(void* const* d_in, const int* in_sizes, int n_in,
                              void* d_out, int out_size, void* d_ws, size_t ws_size,
                              hipStream_t stream) {
  const float* x       = (const float*)d_in[0];
  const int*   y       = (const int*)d_in[1];
  const float* centers = (const float*)d_in[2];
  float* out = (float*)d_out;  // out[0] = loss, out[1..] = ynew as float

  const size_t xb_bytes = (size_t)NPTS * DD * 2;  // 64 MB
  const size_t cb_bytes = (size_t)KC * DD * 2;    // 1 MB
  const size_t need = xb_bytes + cb_bytes + (KC + NPTS / 4) * sizeof(float);

  if (ws_size >= need) {
    uint4* xb      = (uint4*)d_ws;
    uint4* cbp     = (uint4*)((char*)d_ws + xb_bytes);
    float* c2      = (float*)((char*)d_ws + xb_bytes + cb_bytes);
    float* partial = c2 + KC;        // 16384 floats
    prep_kernel<<<16384 + 256, 256, 0, stream>>>(x, y, centers, xb, cbp, c2, partial);
    gemm_argmin<<<NPTS / 128, 256, 0, stream>>>(xb, cbp, c2, out + 1);
    loss_final<<<1, 256, 0, stream>>>(partial, out);
  } else {
    float* c2      = (float*)d_ws;
    float* partial = c2 + KC;
    c2_kernel<<<KC / 4, 256, 0, stream>>>(centers, c2);
    argmin_fb<<<NPTS / 128, 256, 0, stream>>>(x, centers, c2, out + 1);
    loss_partial_fb<<<NPTS / 4, 256, 0, stream>>>(x, y, centers, partial);
    loss_final<<<1, 256, 0, stream>>>(partial, out);
  }
}